// Round 1
// baseline (3861.523 us; speedup 1.0000x reference)
//
#include <hip/hip_runtime.h>

#define Bq   16
#define Nseq 1024
#define Cdim 768
#define NH2  24
#define HD   64
#define W2D  1536
#define KB   16
#define NMB  64

// ---------------- generic f32 tiled GEMM: C[M,N] = A[M,K] @ B[K,N] (+bias) ---
__global__ __launch_bounds__(256) void gemm_f32_kernel(
    const float* __restrict__ A, const float* __restrict__ B,
    const float* __restrict__ bias, float* __restrict__ C,
    int M, int Kd, int Nd)
{
  __shared__ float As[64 * 17];   // [m][kk], padded
  __shared__ float Bs[16 * 65];   // [kk][n], padded
  const int t = threadIdx.x;
  const int tx = t & 15, ty = t >> 4;
  const int bx = blockIdx.x * 64, by = blockIdx.y * 64;
  float acc[4][4] = {};
  for (int k0 = 0; k0 < Kd; k0 += 16) {
#pragma unroll
    for (int r = 0; r < 4; ++r) {
      int q = t + 256 * r;
      int m = q >> 4, kk = q & 15;
      As[m * 17 + kk] = A[(size_t)(by + m) * Kd + k0 + kk];
    }
#pragma unroll
    for (int r = 0; r < 4; ++r) {
      int q = t + 256 * r;
      int kk = q >> 6, n = q & 63;
      Bs[kk * 65 + n] = B[(size_t)(k0 + kk) * Nd + bx + n];
    }
    __syncthreads();
#pragma unroll
    for (int kk = 0; kk < 16; ++kk) {
      float av[4], bv[4];
#pragma unroll
      for (int i2 = 0; i2 < 4; ++i2) av[i2] = As[(ty * 4 + i2) * 17 + kk];
#pragma unroll
      for (int j2 = 0; j2 < 4; ++j2) bv[j2] = Bs[kk * 65 + tx * 4 + j2];
#pragma unroll
      for (int i2 = 0; i2 < 4; ++i2)
#pragma unroll
        for (int j2 = 0; j2 < 4; ++j2)
          acc[i2][j2] += av[i2] * bv[j2];
    }
    __syncthreads();
  }
#pragma unroll
  for (int i2 = 0; i2 < 4; ++i2) {
    int row = by + ty * 4 + i2;
#pragma unroll
    for (int j2 = 0; j2 < 4; ++j2) {
      int col = bx + tx * 4 + j2;
      float v = acc[i2][j2];
      if (bias) v += bias[col];
      C[(size_t)row * Nd + col] = v;
    }
  }
}

// ---------------- lr = sigmoid(xx @ lr_w + lr_b) / hd ------------------------
// xx[b,n,:] = concat(x[b,n,:], x[b,N-1-n,:]); output lr[(b*N+n)*24 + h]
__global__ __launch_bounds__(256) void lr_kernel(
    const float* __restrict__ x, const float* __restrict__ lr_w,
    const float* __restrict__ lr_b, float* __restrict__ lrout)
{
  int idx = blockIdx.x * 256 + threadIdx.x;
  if (idx >= Bq * Nseq * NH2) return;
  int hh = idx % NH2;
  int row = idx / NH2;
  int b = row >> 10, n = row & 1023;
  const float* x1 = x + (size_t)row * Cdim;
  const float* x2 = x + (size_t)(b * Nseq + (Nseq - 1 - n)) * Cdim;
  float acc = lr_b[hh];
  for (int c = 0; c < Cdim; ++c) acc += x1[c] * lr_w[c * NH2 + hh];
  for (int c = 0; c < Cdim; ++c) acc += x2[c] * lr_w[(Cdim + c) * NH2 + hh];
  float sg = 1.f / (1.f + expf(-acc));
  lrout[idx] = sg * (1.f / 64.f);
}

// ---------------- the TTT scan: one block per (b,h) chain --------------------
__global__ __launch_bounds__(256) void ttt_scan_kernel(
    const float* __restrict__ qkv,   // (B,N,2304)
    const float* __restrict__ lrg,   // (B,N,24)
    const float* __restrict__ W1,    // (24,64,64)
    const float* __restrict__ b1g,   // (24,64)
    const float* __restrict__ lnw,   // (24,64)
    const float* __restrict__ lnb,   // (24,64)
    const float* __restrict__ tid,   // (16,)
    float* __restrict__ Zout)        // (B,N,1536)
{
  __shared__ float W[64 * 64];
  __shared__ float sq[16 * 65], sk[16 * 65], sv[16 * 65];
  __shared__ float grad[16 * 64];
  __shared__ float coef[16 * 17];
  __shared__ float bvec[64], gv[64], btv[64];
  __shared__ float lrv[16], tokv[16];
  __shared__ float csl[16 * 32], snl[16 * 32];

  const int t = threadIdx.x;
  const int l = t & 63, w = t >> 6;
  const int bh = blockIdx.x;
  const int b = bh / NH2, h = bh % NH2;

  // ---- init ----
#pragma unroll
  for (int r = 0; r < 16; ++r) W[t + 256 * r] = W1[h * 4096 + t + 256 * r];
  if (t < 64) { bvec[t] = b1g[h * 64 + t]; gv[t] = lnw[h * 64 + t]; btv[t] = lnb[h * 64 + t]; }
  if (t < 16) { float tk = 1.0f / (float)(t + 1) + tid[t]; tokv[t] = tk > 0.f ? tk : 0.f; }
  for (int q = t; q < 512; q += 256) {
    int i = q >> 5, p = q & 31;
    float invp = __expf(-((float)(2 * p) / 64.f) * 9.210340371976184f);  // ln(1e4)
    float ang = (float)i * invp;
    csl[q] = cosf(ang);
    snl[q] = sinf(ang);
  }
  const int chan = (h < 12) ? h * 64 : (h - 12) * 64;
  __syncthreads();

  for (int m = 0; m < NMB; ++m) {
    // ---- load tiles (head gather + flip + rotary) ----
    if (t < 16) lrv[t] = lrg[(size_t)(b * Nseq + m * KB + t) * NH2 + h];
#pragma unroll
    for (int r = 0; r < 4; ++r) {
      int i = 4 * w + r;
      int n = m * KB + i;
      int grow = (h < 12) ? (b * Nseq + n) : (b * Nseq + (Nseq - 1 - n));
      const float* base = qkv + (size_t)grow * 2304 + chan + l;
      float qvv = base[0];
      float kvv = base[768];
      float vvv = base[1536];
      int p = l >> 1;
      float c = csl[i * 32 + p], s = snl[i * 32 + p];
      float qo = __shfl_xor(qvv, 1);
      float ko = __shfl_xor(kvv, 1);
      float sgn = (l & 1) ? 1.f : -1.f;
      sq[i * 65 + l] = qvv * c + qo * s * sgn;
      sk[i * 65 + l] = kvv * c + ko * s * sgn;
      sv[i * 65 + l] = vvv;
    }
    __syncthreads();

    // ---- phase 2: Z1 = xk@W + b, xqW = xq@W (wave w owns rows 4w..4w+3) ----
    float accz[4] = {0.f, 0.f, 0.f, 0.f}, accq[4] = {0.f, 0.f, 0.f, 0.f};
#pragma unroll 8
    for (int c = 0; c < 64; ++c) {
      float wv = W[c * 64 + l];
#pragma unroll
      for (int r = 0; r < 4; ++r) {
        accz[r] += sk[(4 * w + r) * 65 + c] * wv;
        accq[r] += sq[(4 * w + r) * 65 + c] * wv;
      }
    }
    // ---- phase 3: grad = ln_l2_bwd(Z1, xv-xk) ----
#pragma unroll
    for (int r = 0; r < 4; ++r) {
      int i = 4 * w + r;
      float z = accz[r] + bvec[l];
      float s1 = z, s2 = z * z;
#pragma unroll
      for (int o = 1; o < 64; o <<= 1) { s1 += __shfl_xor(s1, o); s2 += __shfl_xor(s2, o); }
      float mu = s1 * (1.f / 64.f);
      float var = s2 * (1.f / 64.f) - mu * mu;
      float rstd = rsqrtf(var + 1e-6f);
      float xh = (z - mu) * rstd;
      float tgt = sv[i * 65 + l] - sk[i * 65 + l];
      float gout = gv[l] * xh + btv[l] - tgt;
      float gxh = gout * gv[l];
      float r1 = gxh, r2 = gxh * xh;
#pragma unroll
      for (int o = 1; o < 64; o <<= 1) { r1 += __shfl_xor(r1, o); r2 += __shfl_xor(r2, o); }
      grad[i * 64 + l] = (64.f * gxh - r1 - xh * r2) * rstd * (1.f / 64.f);
    }
    // ---- phase 4: coef[i][j] = (j<=i) ? tok[i]*lr[j]*(xq_i . xk_j + 1) : 0 ----
    {
      int ii = t >> 4, jj = t & 15;
      float d = 0.f;
#pragma unroll 8
      for (int c = 0; c < 64; ++c) d += sq[ii * 65 + c] * sk[jj * 65 + c];
      coef[ii * 17 + jj] = (jj <= ii) ? tokv[ii] * lrv[jj] * (d + 1.f) : 0.f;
    }
    __syncthreads();

    // ---- phase 5: Z1_bar, LN, output ----
#pragma unroll
    for (int r = 0; r < 4; ++r) {
      int i = 4 * w + r;
      float zb = accq[r] + bvec[l];
#pragma unroll
      for (int j = 0; j < 16; ++j) zb -= coef[i * 17 + j] * grad[j * 64 + l];
      float s1 = zb, s2 = zb * zb;
#pragma unroll
      for (int o = 1; o < 64; o <<= 1) { s1 += __shfl_xor(s1, o); s2 += __shfl_xor(s2, o); }
      float mu = s1 * (1.f / 64.f);
      float var = s2 * (1.f / 64.f) - mu * mu;
      float rstd = rsqrtf(var + 1e-6f);
      float outv = sq[i * 65 + l] + gv[l] * (zb - mu) * rstd + btv[l];
      Zout[(size_t)(b * Nseq + m * KB + i) * W2D + h * 64 + l] = outv;
    }
    __syncthreads();

    // ---- phase 6: W -= (last*xk)^T @ grad ; b -= sum(last*grad) ----
    float t15 = tokv[15];
#pragma unroll
    for (int j2 = 0; j2 < 16; ++j2) {
      int d = w * 16 + j2;
      float acc = 0.f;
#pragma unroll
      for (int k = 0; k < 16; ++k) acc += lrv[k] * sk[k * 65 + d] * grad[k * 64 + l];
      W[d * 64 + l] -= t15 * acc;
    }
    if (w == 0) {
      float acc = 0.f;
#pragma unroll
      for (int k = 0; k < 16; ++k) acc += lrv[k] * grad[k * 64 + l];
      bvec[l] -= t15 * acc;
    }
    __syncthreads();
  }
}

// ---------------- post-LN over W2=1536 ---------------------------------------
__global__ __launch_bounds__(256) void postln_kernel(
    const float* __restrict__ Z, const float* __restrict__ wv,
    const float* __restrict__ bb, float* __restrict__ out)
{
  __shared__ float red[8];
  const int row = blockIdx.x;
  const int t = threadIdx.x;
  const float* zr = Z + (size_t)row * W2D;
  float vals[6];
  float s1 = 0.f, s2 = 0.f;
#pragma unroll
  for (int r = 0; r < 6; ++r) { float v = zr[t + 256 * r]; vals[r] = v; s1 += v; s2 += v * v; }
#pragma unroll
  for (int o = 1; o < 64; o <<= 1) { s1 += __shfl_xor(s1, o); s2 += __shfl_xor(s2, o); }
  if ((t & 63) == 0) { red[t >> 6] = s1; red[4 + (t >> 6)] = s2; }
  __syncthreads();
  s1 = red[0] + red[1] + red[2] + red[3];
  s2 = red[4] + red[5] + red[6] + red[7];
  float mu = s1 * (1.f / 1536.f);
  float var = s2 * (1.f / 1536.f) - mu * mu;
  float rstd = rsqrtf(var + 1e-6f);
  float* orow = out + (size_t)row * W2D;
#pragma unroll
  for (int r = 0; r < 6; ++r) {
    int c = t + 256 * r;
    orow[c] = wv[c] * (vals[r] - mu) * rstd + bb[c];
  }
}

// ---------------- h[b,n,c] = Zln[b,n,c] * Zln[b,N-1-n,768+c] -----------------
__global__ __launch_bounds__(256) void mult_kernel(
    const float* __restrict__ Zln, float* __restrict__ hbuf)
{
  int idx = blockIdx.x * 256 + threadIdx.x;
  int c = idx % Cdim;
  int row = idx / Cdim;     // b*N + n
  int b = row >> 10, n = row & 1023;
  float zf = Zln[(size_t)row * W2D + c];
  float zb = Zln[(size_t)(b * Nseq + (Nseq - 1 - n)) * W2D + Cdim + c];
  hbuf[idx] = zf * zb;
}

// ---------------- launch -----------------------------------------------------
extern "C" void kernel_launch(void* const* d_in, const int* in_sizes, int n_in,
                              void* d_out, int out_size, void* d_ws, size_t ws_size,
                              hipStream_t stream)
{
  const float* x         = (const float*)d_in[0];
  const float* qkv_w     = (const float*)d_in[1];
  const float* proj_w    = (const float*)d_in[2];
  const float* proj_b    = (const float*)d_in[3];
  const float* W1        = (const float*)d_in[4];
  const float* b1        = (const float*)d_in[5];
  const float* ttt_ln_w  = (const float*)d_in[6];
  const float* ttt_ln_b  = (const float*)d_in[7];
  const float* post_ln_w = (const float*)d_in[8];
  const float* post_ln_b = (const float*)d_in[9];
  const float* lr_w      = (const float*)d_in[10];
  const float* lr_b      = (const float*)d_in[11];
  const float* tid       = (const float*)d_in[12];
  float* out = (float*)d_out;
  float* ws  = (float*)d_ws;

  // workspace layout (floats)
  float* qkv   = ws;                       // 16384*2304 = 37,748,736
  float* lrbuf = ws + 37748736;            // 393,216
  float* Zbuf  = ws + 38141952;            // 25,165,824
  // after the scan, the qkv region is dead — reuse it:
  float* Zln   = ws;                       // 25,165,824
  float* hbuf  = ws + 25165824;            // 12,582,912 (fits exactly in qkv region)

  const int Mrows = Bq * Nseq;             // 16384

  dim3 g1(3 * Cdim / 64, Mrows / 64);      // (36, 256)
  gemm_f32_kernel<<<g1, 256, 0, stream>>>(x, qkv_w, nullptr, qkv, Mrows, Cdim, 3 * Cdim);

  lr_kernel<<<(Mrows * NH2 + 255) / 256, 256, 0, stream>>>(x, lr_w, lr_b, lrbuf);

  ttt_scan_kernel<<<Bq * NH2, 256, 0, stream>>>(qkv, lrbuf, W1, b1, ttt_ln_w, ttt_ln_b, tid, Zbuf);

  postln_kernel<<<Mrows, 256, 0, stream>>>(Zbuf, post_ln_w, post_ln_b, Zln);

  mult_kernel<<<(Mrows * Cdim) / 256, 256, 0, stream>>>(Zln, hbuf);

  dim3 g2(Cdim / 64, Mrows / 64);          // (12, 256)
  gemm_f32_kernel<<<g2, 256, 0, stream>>>(hbuf, proj_w, proj_b, out, Mrows, Cdim, Cdim);
}